// Round 21
// baseline (117.519 us; speedup 1.0000x reference)
//
#include <hip/hip_runtime.h>
#include <math.h>

#define SPAT 1600
#define BSZ 8
#define DM 256
#define NH 8
#define DH 32
#define NC16 100  // SPAT/16 c-tiles in K=16 V^T fragment layout

typedef __attribute__((ext_vector_type(8))) short bf16x8;
typedef __attribute__((ext_vector_type(4))) short bf16x4;
typedef __attribute__((ext_vector_type(4))) float f32x4;
typedef __attribute__((ext_vector_type(4))) unsigned short u16x4;

static __device__ __forceinline__ unsigned short f2bf(float x) {
  unsigned u = __float_as_uint(x);
  unsigned r = (u + 0x7fff + ((u >> 16) & 1)) >> 16;
  return (unsigned short)r;
}
static __device__ __forceinline__ float bf2f(unsigned short h) {
  return __uint_as_float(((unsigned)h) << 16);
}

// -------- K1/P0 fused: logits + splitq + prepw (independent inputs) --------
__global__ __launch_bounds__(256) void prep_logits_kernel(
    const float* __restrict__ k, const float* __restrict__ Wp,
    const float* __restrict__ bp, float* __restrict__ logits,
    const float* __restrict__ q,
    const float* __restrict__ Wq, const float* __restrict__ Wk,
    const float* __restrict__ Wv, const float* __restrict__ Wo,
    unsigned short* __restrict__ qfh, unsigned short* __restrict__ qfl,
    unsigned short* __restrict__ WTh, unsigned short* __restrict__ WTl)
{
  int bx = blockIdx.x;
  if (bx < 3200) {
    int wave = threadIdx.x >> 6, lane = threadIdx.x & 63;
    int idx = bx * 4 + wave;                 // 0..12799
    int b = idx / SPAT, s = idx - b * SPAT;
    const float4 kv = *(const float4*)(k + (s * BSZ + b) * DM + lane * 4);
    const float4 wv = *(const float4*)(Wp + lane * 4);
    float sum = kv.x * wv.x + kv.y * wv.y + kv.z * wv.z + kv.w * wv.w;
    #pragma unroll
    for (int off = 32; off; off >>= 1) sum += __shfl_xor(sum, off);
    if (lane == 0) logits[idx] = sum + bp[0];
  } else if (bx < 4800) {
    int tg = (bx - 3200) * 256 + threadIdx.x;
    int row = tg >> 5;                       // b*1600+s
    int d0 = (tg & 31) * 8;
    int b = row / SPAT, s = row - b * SPAT;
    const float* src = q + (size_t)(s * BSZ + b) * DM + d0;
    float4 a = *(const float4*)src;
    float4 c = *(const float4*)(src + 4);
    float xs[8] = {a.x, a.y, a.z, a.w, c.x, c.y, c.z, c.w};
    bf16x8 hv, lv;
    #pragma unroll
    for (int j = 0; j < 8; ++j) {
      unsigned short hb = f2bf(xs[j]);
      hv[j] = (short)hb;
      lv[j] = (short)f2bf(xs[j] - bf2f(hb));
    }
    size_t dst = (((size_t)(row >> 4) * 8 + (d0 >> 5)) * 64
                  + ((d0 >> 3) & 3) * 16 + (row & 15)) * 8;
    *(bf16x8*)(qfh + dst) = hv;
    *(bf16x8*)(qfl + dst) = lv;
  } else {
    int mb = bx - 4800;
    int mat = mb >> 3, ktile = mb & 7;
    const float* W = (mat == 0) ? Wq : (mat == 1) ? Wk : (mat == 2) ? Wv : Wo;
    int n = threadIdx.x;
    int ntile = n >> 4, sig = n & 15;
    size_t base = (((size_t)(mat * 16 + ntile) * 8 + ktile) * 64 + sig) * 8;
    #pragma unroll 4
    for (int i = 0; i < 32; ++i) {
      int kk = ktile * 32 + i;
      float x = W[kk * DM + n];
      unsigned short hb = f2bf(x);
      size_t dst = base + (size_t)(i >> 3) * 128 + (i & 7);
      WTh[dst] = hb;
      WTl[dst] = (unsigned short)f2bf(x - bf2f(hb));
    }
  }
}

// -------- K2: per-batch softmax -> entropy -> gaussian conv (512 thr) --------
__global__ __launch_bounds__(512) void entropy_kernel(
    const float* __restrict__ logits, const float* __restrict__ gk,
    float* __restrict__ smooth)
{
  int b = blockIdx.x;
  int t = threadIdx.x;
  const float* L = logits + b * SPAT;
  __shared__ float entpad[SPAT + 28];
  __shared__ float red[512];

  for (int i = t; i < SPAT + 28; i += 512) entpad[i] = 0.f;

  float m = -INFINITY;
  for (int i = t; i < SPAT; i += 512) m = fmaxf(m, L[i]);
  red[t] = m; __syncthreads();
  for (int o = 256; o; o >>= 1) { if (t < o) red[t] = fmaxf(red[t], red[t + o]); __syncthreads(); }
  m = red[0]; __syncthreads();

  float lsum = 0.f;
  for (int i = t; i < SPAT; i += 512) {
    float e = expf(L[i] - m);
    entpad[14 + i] = e;
    lsum += e;
  }
  red[t] = lsum; __syncthreads();
  for (int o = 256; o; o >>= 1) { if (t < o) red[t] += red[t + o]; __syncthreads(); }
  float S = red[0]; __syncthreads();

  for (int i = t; i < SPAT; i += 512) {
    float p = entpad[14 + i] / S + 1e-8f;
    entpad[14 + i] = -p * logf(p) / 0.6931471805599453f;
  }
  __syncthreads();

  for (int i = t; i < SPAT; i += 512) {
    float acc = 0.f;
    #pragma unroll
    for (int u = 0; u < 29; ++u) acc += entpad[i + u] * gk[28 - u];
    smooth[b * SPAT + i] = acc;
  }
}

// -------- K3: cluster size; wave w = batch w, shfl-reduce, no atomics --------
__global__ __launch_bounds__(512) void clsize_kernel(
    const float* __restrict__ smooth, const float* __restrict__ sobel,
    int* __restrict__ meta)
{
  __shared__ int cnts[8];
  int t = threadIdx.x;
  int w = t >> 6, lane = t & 63;
  float sb0 = sobel[0], sb1 = sobel[1], sb2 = sobel[2];
  const float* sm = smooth + w * SPAT;
  int local = 0;
  for (int i = 1 + lane; i < SPAT; i += 64) {
    float smL = (i >= 2) ? sm[i - 2] : 0.f;
    float a = sm[i - 1];
    float c = sm[i];
    float smR = (i + 1 < SPAT) ? sm[i + 1] : 0.f;
    float stepPrev = smL * sb2 + a * sb1 + c * sb0;
    float stepCur  = a * sb2 + c * sb1 + smR * sb0;
    local += ((stepPrev > 0.f) != (stepCur > 0.f));
  }
  #pragma unroll
  for (int off = 32; off; off >>= 1) local += __shfl_xor(local, off);
  if (lane == 0) cnts[w] = local;
  __syncthreads();
  if (t == 0) {
    float msum = 0.f;
    for (int b = 0; b < BSZ; ++b) msum += 1600.f / (float)(cnts[b] + 1);
    float mean = msum / 8.f;
    int C = (int)rintf(mean);
    if (C < 1) C = 1;
    int rem = SPAT % C;
    meta[0] = C; meta[1] = rem / 2; meta[2] = rem; meta[3] = (SPAT - rem) / C;
  }
}

// -------- K4: cluster pooling; serial per-thread softmax (no barriers),
// emits kc/vc as bf16 hi/lo A-fragments --------
__global__ __launch_bounds__(256) void cluster_kernel(
    const float* __restrict__ k, const float* __restrict__ v,
    const float* __restrict__ smooth, const int* __restrict__ meta,
    unsigned short* __restrict__ kcfh, unsigned short* __restrict__ kcfl,
    unsigned short* __restrict__ vcfh, unsigned short* __restrict__ vcfl)
{
  int c = blockIdx.x, b = blockIdx.y;
  int C = meta[0], lo = meta[1], n_cl = meta[3];
  if (c >= n_cl) return;
  const float* sm = smooth + b * SPAT + lo + c * C;

  float m = sm[0];
  for (int j = 1; j < C; ++j) m = fmaxf(m, sm[j]);
  float S = 0.f;
  for (int j = 0; j < C; ++j) S += __expf(sm[j] - m);
  float invS = 1.f / S;

  int d = threadIdx.x;
  int s0 = lo + c * C;
  const float* kp = k + (s0 * BSZ + b) * DM + d;
  const float* vp = v + (s0 * BSZ + b) * DM + d;
  float ak = 0.f, av = 0.f;
  for (int j = 0; j < C; ++j) {
    float wj = __expf(sm[j] - m) * invS;
    ak += wj * kp[0];
    av += wj * vp[0];
    kp += BSZ * DM; vp += BSZ * DM;
  }
  int rowg = b * SPAT + c;
  size_t dst = (((size_t)(rowg >> 4) * 8 + (d >> 5)) * 64
                + ((d >> 3) & 3) * 16 + (rowg & 15)) * 8 + (d & 7);
  unsigned short hb = f2bf(ak);
  kcfh[dst] = hb; kcfl[dst] = (unsigned short)f2bf(ak - bf2f(hb));
  hb = f2bf(av);
  vcfh[dst] = hb; vcfl[dst] = (unsigned short)f2bf(av - bf2f(hb));
}

// -------- shared GEMM body: fragment-linear operands, bf16x3, unroll 2 ----
static __device__ __forceinline__ void gemm_body(
    const unsigned short* __restrict__ Afh, const unsigned short* __restrict__ Afl,
    const unsigned short* __restrict__ Bfh, const unsigned short* __restrict__ Bfl,
    const float* __restrict__ bias,
    unsigned short* __restrict__ Oh, unsigned short* __restrict__ Ol,
    float* __restrict__ Of, int epi, int skipcl, const int* __restrict__ meta)
{
  int row0blk = blockIdx.x * 64;
  if (skipcl && (row0blk % SPAT) >= meta[3]) return;
  int wv = threadIdx.x >> 6, l = threadIdx.x & 63;
  int g = l >> 4, sig = l & 15;
  int row0 = row0blk + wv * 16;
  int rtile = row0 >> 4;
  int col0 = blockIdx.y * 64;
  int ntile0 = col0 >> 4;

  f32x4 acc[4] = {{0.f,0.f,0.f,0.f},{0.f,0.f,0.f,0.f},{0.f,0.f,0.f,0.f},{0.f,0.f,0.f,0.f}};

  #pragma unroll 2
  for (int kt = 0; kt < 8; ++kt) {
    size_t ao = (((size_t)rtile * 8 + kt) * 64 + l) * 8;
    bf16x8 ah = *(const bf16x8*)(Afh + ao);
    bf16x8 al = *(const bf16x8*)(Afl + ao);
    #pragma unroll
    for (int nt = 0; nt < 4; ++nt) {
      size_t bo = (((size_t)(ntile0 + nt) * 8 + kt) * 64 + l) * 8;
      bf16x8 bh = *(const bf16x8*)(Bfh + bo);
      bf16x8 bl = *(const bf16x8*)(Bfl + bo);
      acc[nt] = __builtin_amdgcn_mfma_f32_16x16x32_bf16(ah, bh, acc[nt], 0, 0, 0);
      acc[nt] = __builtin_amdgcn_mfma_f32_16x16x32_bf16(al, bh, acc[nt], 0, 0, 0);
      acc[nt] = __builtin_amdgcn_mfma_f32_16x16x32_bf16(ah, bl, acc[nt], 0, 0, 0);
    }
  }

  int bb = row0 / SPAT;
  int sbase = row0 - bb * SPAT + 4 * g;
  #pragma unroll
  for (int nt = 0; nt < 4; ++nt) {
    int n = col0 + nt * 16 + sig;
    float bi = bias[n];
    if (epi == 0) {
      int h = n >> 5, dl = n & 31;
      size_t base = (size_t)(bb * NH + h) * SPAT * DH + dl;
      #pragma unroll
      for (int r = 0; r < 4; ++r) {
        float x = acc[nt][r] + bi;
        unsigned short hb = f2bf(x);
        size_t dst = base + (size_t)(sbase + r) * DH;
        Oh[dst] = hb;
        Ol[dst] = (unsigned short)f2bf(x - bf2f(hb));
      }
    } else if (epi == 1) {
      int h = n >> 5;
      int bh = bb * NH + h;
      int dhalf = (n & 31) >> 4;
      int mrow = n & 15;
      #pragma unroll
      for (int r = 0; r < 4; ++r) {
        int c = sbase + r;
        float x = acc[nt][r] + bi;
        unsigned short hb = f2bf(x);
        size_t dst = ((((size_t)bh * NC16 + (c >> 4)) * 2 + dhalf) * 64
                      + ((c >> 2) & 3) * 16 + mrow) * 4 + (c & 3);
        Oh[dst] = hb;
        Ol[dst] = (unsigned short)f2bf(x - bf2f(hb));
      }
    } else {
      #pragma unroll
      for (int r = 0; r < 4; ++r) {
        float x = acc[nt][r] + bi;
        Of[(size_t)((sbase + r) * BSZ + bb) * DM + n] = x;
      }
    }
  }
}

// -------- K5a: fused Q/K/V projection GEMMs (blockIdx.z selects) --------
__global__ __launch_bounds__(256) void mfma_gemm_qkv_kernel(
    const unsigned short* __restrict__ qfh, const unsigned short* __restrict__ qfl,
    const unsigned short* __restrict__ kcfh, const unsigned short* __restrict__ kcfl,
    const unsigned short* __restrict__ vcfh, const unsigned short* __restrict__ vcfl,
    const unsigned short* __restrict__ WTfh, const unsigned short* __restrict__ WTfl,
    const float* __restrict__ bq, const float* __restrict__ bk, const float* __restrict__ bv,
    unsigned short* __restrict__ Qh, unsigned short* __restrict__ Ql,
    unsigned short* __restrict__ Kh, unsigned short* __restrict__ Kl,
    unsigned short* __restrict__ Vth, unsigned short* __restrict__ Vtl,
    const int* __restrict__ meta)
{
  int z = blockIdx.z;
  if (z == 0) {
    gemm_body(qfh, qfl, WTfh, WTfl, bq, Qh, Ql, nullptr, 0, 0, meta);
  } else if (z == 1) {
    gemm_body(kcfh, kcfl, WTfh + DM * DM, WTfl + DM * DM, bk, Kh, Kl, nullptr, 0, 1, meta);
  } else {
    gemm_body(vcfh, vcfl, WTfh + 2 * DM * DM, WTfl + 2 * DM * DM, bv, Vth, Vtl, nullptr, 1, 1, meta);
  }
}

// -------- K5b: output GEMM (epi=2, fp32 out + transpose) --------
__global__ __launch_bounds__(256) void mfma_gemm_o_kernel(
    const unsigned short* __restrict__ Afh, const unsigned short* __restrict__ Afl,
    const unsigned short* __restrict__ Bfh, const unsigned short* __restrict__ Bfl,
    const float* __restrict__ bias, float* __restrict__ Of,
    const int* __restrict__ meta)
{
  gemm_body(Afh, Afl, Bfh, Bfl, bias, nullptr, nullptr, Of, 2, 0, meta);
}

// -------- K6: MFMA attention, 2-way cluster-split, 8 waves/block --------
// Round-20 state: attn latency-bound, TLP capped by work decomposition
// (6400 waves). This doubles waves to 12800 at UNCHANGED per-wave VGPR:
// wave w = (s-group w&3, cluster-half w>>2); halves merged per-lane via
// LDS with online-softmax rescale (round-6-proven pattern). XCD-pinned
// grid (bh,sblk) kept; per-half wave stagger kept.
__global__ __launch_bounds__(512) void attn_mfma_kernel(
    const unsigned short* __restrict__ Qh, const unsigned short* __restrict__ Ql,
    const unsigned short* __restrict__ Kh, const unsigned short* __restrict__ Kl,
    const unsigned short* __restrict__ Vth, const unsigned short* __restrict__ Vtl,
    const int* __restrict__ meta,
    unsigned short* __restrict__ ctxfh, unsigned short* __restrict__ ctxfl)
{
  __shared__ float mrg[4][64][10];          // half-1 partials: m,l,o0,o1
  int bh = blockIdx.x;                      // 0..63 -> XCD = bh % 8
  int b = bh >> 3, h = bh & 7;
  int t = threadIdx.x;
  int w = t >> 6, l = t & 63;
  int sw = w & 3, half = w >> 2;
  int g = l >> 4, sig = l & 15;
  int n_cl = meta[3];
  int s = blockIdx.y * 64 + sw * 16 + sig;  // 25*64 = 1600

  size_t qoff = ((size_t)bh * SPAT + s) * DH + g * 8;
  bf16x8 qh = *(const bf16x8*)(Qh + qoff);
  bf16x8 ql = *(const bf16x8*)(Ql + qoff);

  const unsigned short* Kbh = Kh + (size_t)bh * SPAT * DH;
  const unsigned short* Kbl = Kl + (size_t)bh * SPAT * DH;
  const unsigned short* Vbh = Vth + (size_t)bh * NC16 * 2 * 64 * 4;
  const unsigned short* Vbl = Vtl + (size_t)bh * NC16 * 2 * 64 * 4;

  f32x4 o0 = {0.f, 0.f, 0.f, 0.f}, o1 = {0.f, 0.f, 0.f, 0.f};
  float m = -1e30f, lsum = 0.f;

  int nch = (n_cl + 63) >> 6;
  int nch2 = (nch + 1) >> 1;
  int base = half ? nch2 : 0;
  int cnt  = half ? (nch - nch2) : nch2;
  int start = (cnt > 0) ? ((sw * cnt) >> 2) : 0;

  for (int i = 0; i < cnt; ++i) {
    int ci = start + i;
    if (ci >= cnt) ci -= cnt;
    int c0 = (base + ci) * 64;

    // ---- QK^T: rows cr = c0+ct*16+sig <= 1599 always (c0 <= 1536) ----
    f32x4 sc[4];
    __builtin_amdgcn_s_setprio(1);
    #pragma unroll
    for (int ct = 0; ct < 4; ++ct) {
      size_t ko = (size_t)(c0 + ct * 16 + sig) * DH + g * 8;
      bf16x8 kh = *(const bf16x8*)(Kbh + ko);
      bf16x8 kl = *(const bf16x8*)(Kbl + ko);
      f32x4 a = {0.f, 0.f, 0.f, 0.f};
      a = __builtin_amdgcn_mfma_f32_16x16x32_bf16(kh, qh, a, 0, 0, 0);
      a = __builtin_amdgcn_mfma_f32_16x16x32_bf16(kh, ql, a, 0, 0, 0);
      a = __builtin_amdgcn_mfma_f32_16x16x32_bf16(kl, qh, a, 0, 0, 0);
      sc[ct] = a;
    }
    __builtin_amdgcn_s_setprio(0);

    // ---- V A-frags for this chunk: issue BEFORE softmax (independent) ----
    bf16x4 vfh[4][2], vfl[4][2];
    #pragma unroll
    for (int ct = 0; ct < 4; ++ct) {
      int c16 = (c0 >> 4) + ct;             // <= 99, always in-buffer
      #pragma unroll
      for (int dh2 = 0; dh2 < 2; ++dh2) {
        size_t vo = (((size_t)c16 * 2 + dh2) * 64 + l) * 4;
        vfh[ct][dh2] = *(const bf16x4*)(Vbh + vo);
        vfl[ct][dh2] = *(const bf16x4*)(Vbl + vo);
      }
    }

    if (c0 + 64 > n_cl) {                   // tail chunk only: mask
      #pragma unroll
      for (int ct = 0; ct < 4; ++ct) {
        #pragma unroll
        for (int r = 0; r < 4; ++r) {
          int c = c0 + ct * 16 + g * 4 + r;
          if (c >= n_cl) sc[ct][r] = -INFINITY;
        }
      }
    }
    float mc = sc[0][0];
    #pragma unroll
    for (int ct = 0; ct < 4; ++ct) {
      #pragma unroll
      for (int r = 0; r < 4; ++r) mc = fmaxf(mc, sc[ct][r]);
    }
    mc = fmaxf(mc, __shfl_xor(mc, 16));
    mc = fmaxf(mc, __shfl_xor(mc, 32));
    float nm = fmaxf(m, mc);
    float corr = __expf(m - nm);
    m = nm;
    lsum *= corr; o0 *= corr; o1 *= corr;
    float ls0 = 0.f, ls1 = 0.f;
    #pragma unroll
    for (int ct = 0; ct < 4; ++ct) {
      #pragma unroll
      for (int r = 0; r < 4; ++r) {
        float p = __expf(sc[ct][r] - m);
        sc[ct][r] = p;
        if (ct < 2) ls0 += p; else ls1 += p;
      }
    }
    lsum += ls0 + ls1;

    // ---- PV: P already in B-frag layout for 16x16x16 (k = 4g+j) ----
    __builtin_amdgcn_s_setprio(1);
    #pragma unroll
    for (int ct = 0; ct < 4; ++ct) {
      if (c0 + ct * 16 >= n_cl) continue;   // wave-uniform skip
      bf16x4 pb;
      #pragma unroll
      for (int j = 0; j < 4; ++j) pb[j] = (short)f2bf(sc[ct][j]);
      o0 = __builtin_amdgcn_mfma_f32_16x16x16bf16_1k(vfh[ct][0], pb, o0, 0, 0, 0);
      o0 = __builtin_amdgcn_mfma_f32_16x16x16bf16_1k(vfl[ct][0], pb, o0, 0, 0, 0);
      o1 = __builtin_amdgcn_mfma_f32_16x16x16bf16_1k(vfh[ct][1], pb, o1, 0, 0, 0);
      o1 = __builtin_amdgcn_mfma_f32_16x16x16bf16_1k(vfl[ct][1], pb, o1, 0, 0, 0);
    }
    __builtin_amdgcn_s_setprio(0);
  }

  // ---- merge halves through LDS (per-lane online-softmax rescale) ----
  if (half == 1) {
    float* d = mrg[sw][l];
    d[0] = m; d[1] = lsum;
    d[2] = o0[0]; d[3] = o0[1]; d[4] = o0[2]; d[5] = o0[3];
    d[6] = o1[0]; d[7] = o1[1]; d[8] = o1[2]; d[9] = o1[3];
  }
  __syncthreads();
  if (half == 1) return;

  const float* sx = mrg[sw][l];
  float m1 = sx[0], l1 = sx[1];
  float M = fmaxf(m, m1);
  float f0 = __expf(m - M), f1 = __expf(m1 - M);  // empty half: f=0
  float L = lsum * f0 + l1 * f1;
  o0[0] = o0[0] * f0 + sx[2] * f1; o0[1] = o0[1] * f0 + sx[3] * f1;
  o0[2] = o0[2] * f0 + sx[4] * f1; o0[3] = o0[3] * f0 + sx[5] * f1;
  o1[0] = o1[0] * f0 + sx[6] * f1; o1[1] = o1[1] * f0 + sx[7] * f1;
  o1[2] = o1[2] * f0 + sx[8] * f1; o1[3] = o1[3] * f0 + sx[9] * f1;

  // ---- finalize: cross-group denom, write O^T frags into ctx layout ----
  L += __shfl_xor(L, 16);
  L += __shfl_xor(L, 32);
  float inv = 1.f / (L * 32.f);
  int rowg = b * SPAT + s;                  // rowg&15 == sig
  size_t tb = (((size_t)(rowg >> 4) * 8 + h) * 64 + sig) * 8 + (g & 1) * 4;
  size_t off0 = tb + (size_t)(g >> 1) * 128;        // d = 4g+r  (ktile=h)
  size_t off1 = tb + (size_t)(2 + (g >> 1)) * 128;  // d = 16+4g+r
  u16x4 hv0, lv0, hv1, lv1;
  #pragma unroll
  for (int r = 0; r < 4; ++r) {
    float x0 = o0[r] * inv;
    unsigned short h0 = f2bf(x0);
    hv0[r] = h0; lv0[r] = (unsigned short)f2bf(x0 - bf2f(h0));
    float x1 = o1[r] * inv;
    unsigned short h1 = f2bf(x1);
    hv1[r] = h1; lv1[r] = (unsigned short)f2bf(x1 - bf2f(h1));
  }
  *(u16x4*)(ctxfh + off0) = hv0;
  *(u16x4*)(ctxfl + off0) = lv0;
  *(u16x4*)(ctxfh + off1) = hv1;
  *(u16x4*)(ctxfl + off1) = lv1;
}

extern "C" void kernel_launch(void* const* d_in, const int* in_sizes, int n_in,
                              void* d_out, int out_size, void* d_ws, size_t ws_size,
                              hipStream_t stream) {
  const float* q  = (const float*)d_in[0];
  const float* k  = (const float*)d_in[1];
  const float* v  = (const float*)d_in[2];
  const float* Wq = (const float*)d_in[5];
  const float* bq = (const float*)d_in[6];
  const float* Wk = (const float*)d_in[7];
  const float* bk = (const float*)d_in[8];
  const float* Wv = (const float*)d_in[9];
  const float* bv = (const float*)d_in[10];
  const float* Wo = (const float*)d_in[11];
  const float* bo = (const float*)d_in[12];
  const float* Wp = (const float*)d_in[13];
  const float* bp = (const float*)d_in[14];
  const float* gk = (const float*)d_in[15];
  const float* sb = (const float*)d_in[16];
  float* out = (float*)d_out;

  const size_t NE = (size_t)BSZ * SPAT * DM;                 // 3276800
  char* ws = (char*)d_ws;
  int*   meta   = (int*)ws;                                  // 256 B
  float* logits = (float*)(ws + 256);                        // 12800 f32
  float* smooth = logits + BSZ * SPAT;                       // 12800 f32
  unsigned short* kcfh = (unsigned short*)(ws + 256 + 2 * BSZ * SPAT * 4);
  unsigned short* kcfl = kcfh + NE;
  unsigned short* vcfh = kcfl + NE;
  unsigned short* vcfl = vcfh + NE;
  unsigned short* qfh  = vcfl + NE;
  unsigned short* qfl  = qfh + NE;
  unsigned short* Qh   = qfl + NE;
  unsigned short* Ql   = Qh + NE;
  unsigned short* Kh   = Ql + NE;
  unsigned short* Kl   = Kh + NE;
  unsigned short* Vth  = Kl + NE;   // NOT aliased: QKV GEMMs fused in one
  unsigned short* Vtl  = Vth + NE;  // dispatch — z=0 reads qf while z=2 writes
  unsigned short* WTfh = Vtl + NE;                           // 4*65536 u16
  unsigned short* WTfl = WTfh + 4 * DM * DM;
  unsigned short* ctxfh = kcfh;     // alias kcf (dead after fused QKV GEMM)
  unsigned short* ctxfl = kcfl;

  prep_logits_kernel<<<4832, 256, 0, stream>>>(
      k, Wp, bp, logits, q, Wq, Wk, Wv, Wo, qfh, qfl, WTfh, WTfl);
  entropy_kernel<<<BSZ, 512, 0, stream>>>(logits, gk, smooth);
  clsize_kernel<<<1, 512, 0, stream>>>(smooth, sb, meta);
  cluster_kernel<<<dim3(SPAT, BSZ), 256, 0, stream>>>(
      k, v, smooth, meta, kcfh, kcfl, vcfh, vcfl);
  mfma_gemm_qkv_kernel<<<dim3(200, 4, 3), 256, 0, stream>>>(
      qfh, qfl, kcfh, kcfl, vcfh, vcfl, WTfh, WTfl, bq, bk, bv,
      Qh, Ql, Kh, Kl, Vth, Vtl, meta);
  attn_mfma_kernel<<<dim3(64, 25), 512, 0, stream>>>(
      Qh, Ql, Kh, Kl, Vth, Vtl, meta, ctxfh, ctxfl);
  mfma_gemm_o_kernel<<<dim3(200, 4), 256, 0, stream>>>(
      ctxfh, ctxfl, WTfh + 3 * DM * DM, WTfl + 3 * DM * DM, bo, out, meta);
}

// Round 22
// 115.766 us; speedup vs baseline: 1.0151x; 1.0151x over previous
//
#include <hip/hip_runtime.h>
#include <math.h>

#define SPAT 1600
#define BSZ 8
#define DM 256
#define NH 8
#define DH 32
#define NC16 100  // SPAT/16 c-tiles in K=16 V^T fragment layout

typedef __attribute__((ext_vector_type(8))) short bf16x8;
typedef __attribute__((ext_vector_type(4))) short bf16x4;
typedef __attribute__((ext_vector_type(4))) float f32x4;
typedef __attribute__((ext_vector_type(4))) unsigned short u16x4;

static __device__ __forceinline__ unsigned short f2bf(float x) {
  unsigned u = __float_as_uint(x);
  unsigned r = (u + 0x7fff + ((u >> 16) & 1)) >> 16;
  return (unsigned short)r;
}
static __device__ __forceinline__ float bf2f(unsigned short h) {
  return __uint_as_float(((unsigned)h) << 16);
}

// -------- K1/P0 fused: logits + splitq + prepw (independent inputs) --------
__global__ __launch_bounds__(256) void prep_logits_kernel(
    const float* __restrict__ k, const float* __restrict__ Wp,
    const float* __restrict__ bp, float* __restrict__ logits,
    const float* __restrict__ q,
    const float* __restrict__ Wq, const float* __restrict__ Wk,
    const float* __restrict__ Wv, const float* __restrict__ Wo,
    unsigned short* __restrict__ qfh, unsigned short* __restrict__ qfl,
    unsigned short* __restrict__ WTh, unsigned short* __restrict__ WTl)
{
  int bx = blockIdx.x;
  if (bx < 3200) {
    int wave = threadIdx.x >> 6, lane = threadIdx.x & 63;
    int idx = bx * 4 + wave;                 // 0..12799
    int b = idx / SPAT, s = idx - b * SPAT;
    const float4 kv = *(const float4*)(k + (s * BSZ + b) * DM + lane * 4);
    const float4 wv = *(const float4*)(Wp + lane * 4);
    float sum = kv.x * wv.x + kv.y * wv.y + kv.z * wv.z + kv.w * wv.w;
    #pragma unroll
    for (int off = 32; off; off >>= 1) sum += __shfl_xor(sum, off);
    if (lane == 0) logits[idx] = sum + bp[0];
  } else if (bx < 4800) {
    int tg = (bx - 3200) * 256 + threadIdx.x;
    int row = tg >> 5;                       // b*1600+s
    int d0 = (tg & 31) * 8;
    int b = row / SPAT, s = row - b * SPAT;
    const float* src = q + (size_t)(s * BSZ + b) * DM + d0;
    float4 a = *(const float4*)src;
    float4 c = *(const float4*)(src + 4);
    float xs[8] = {a.x, a.y, a.z, a.w, c.x, c.y, c.z, c.w};
    bf16x8 hv, lv;
    #pragma unroll
    for (int j = 0; j < 8; ++j) {
      unsigned short hb = f2bf(xs[j]);
      hv[j] = (short)hb;
      lv[j] = (short)f2bf(xs[j] - bf2f(hb));
    }
    size_t dst = (((size_t)(row >> 4) * 8 + (d0 >> 5)) * 64
                  + ((d0 >> 3) & 3) * 16 + (row & 15)) * 8;
    *(bf16x8*)(qfh + dst) = hv;
    *(bf16x8*)(qfl + dst) = lv;
  } else {
    int mb = bx - 4800;
    int mat = mb >> 3, ktile = mb & 7;
    const float* W = (mat == 0) ? Wq : (mat == 1) ? Wk : (mat == 2) ? Wv : Wo;
    int n = threadIdx.x;
    int ntile = n >> 4, sig = n & 15;
    size_t base = (((size_t)(mat * 16 + ntile) * 8 + ktile) * 64 + sig) * 8;
    #pragma unroll 4
    for (int i = 0; i < 32; ++i) {
      int kk = ktile * 32 + i;
      float x = W[kk * DM + n];
      unsigned short hb = f2bf(x);
      size_t dst = base + (size_t)(i >> 3) * 128 + (i & 7);
      WTh[dst] = hb;
      WTl[dst] = (unsigned short)f2bf(x - bf2f(hb));
    }
  }
}

// -------- K2: per-batch softmax -> entropy -> gaussian conv (512 thr) --------
__global__ __launch_bounds__(512) void entropy_kernel(
    const float* __restrict__ logits, const float* __restrict__ gk,
    float* __restrict__ smooth)
{
  int b = blockIdx.x;
  int t = threadIdx.x;
  const float* L = logits + b * SPAT;
  __shared__ float entpad[SPAT + 28];
  __shared__ float red[512];

  for (int i = t; i < SPAT + 28; i += 512) entpad[i] = 0.f;

  float m = -INFINITY;
  for (int i = t; i < SPAT; i += 512) m = fmaxf(m, L[i]);
  red[t] = m; __syncthreads();
  for (int o = 256; o; o >>= 1) { if (t < o) red[t] = fmaxf(red[t], red[t + o]); __syncthreads(); }
  m = red[0]; __syncthreads();

  float lsum = 0.f;
  for (int i = t; i < SPAT; i += 512) {
    float e = expf(L[i] - m);
    entpad[14 + i] = e;
    lsum += e;
  }
  red[t] = lsum; __syncthreads();
  for (int o = 256; o; o >>= 1) { if (t < o) red[t] += red[t + o]; __syncthreads(); }
  float S = red[0]; __syncthreads();

  for (int i = t; i < SPAT; i += 512) {
    float p = entpad[14 + i] / S + 1e-8f;
    entpad[14 + i] = -p * logf(p) / 0.6931471805599453f;
  }
  __syncthreads();

  for (int i = t; i < SPAT; i += 512) {
    float acc = 0.f;
    #pragma unroll
    for (int u = 0; u < 29; ++u) acc += entpad[i + u] * gk[28 - u];
    smooth[b * SPAT + i] = acc;
  }
}

// -------- K3: cluster size; wave w = batch w, shfl-reduce, no atomics --------
__global__ __launch_bounds__(512) void clsize_kernel(
    const float* __restrict__ smooth, const float* __restrict__ sobel,
    int* __restrict__ meta)
{
  __shared__ int cnts[8];
  int t = threadIdx.x;
  int w = t >> 6, lane = t & 63;
  float sb0 = sobel[0], sb1 = sobel[1], sb2 = sobel[2];
  const float* sm = smooth + w * SPAT;
  int local = 0;
  for (int i = 1 + lane; i < SPAT; i += 64) {
    float smL = (i >= 2) ? sm[i - 2] : 0.f;
    float a = sm[i - 1];
    float c = sm[i];
    float smR = (i + 1 < SPAT) ? sm[i + 1] : 0.f;
    float stepPrev = smL * sb2 + a * sb1 + c * sb0;
    float stepCur  = a * sb2 + c * sb1 + smR * sb0;
    local += ((stepPrev > 0.f) != (stepCur > 0.f));
  }
  #pragma unroll
  for (int off = 32; off; off >>= 1) local += __shfl_xor(local, off);
  if (lane == 0) cnts[w] = local;
  __syncthreads();
  if (t == 0) {
    float msum = 0.f;
    for (int b = 0; b < BSZ; ++b) msum += 1600.f / (float)(cnts[b] + 1);
    float mean = msum / 8.f;
    int C = (int)rintf(mean);
    if (C < 1) C = 1;
    int rem = SPAT % C;
    meta[0] = C; meta[1] = rem / 2; meta[2] = rem; meta[3] = (SPAT - rem) / C;
  }
}

// -------- K4: cluster pooling; serial per-thread softmax (no barriers),
// emits kc/vc as bf16 hi/lo A-fragments --------
__global__ __launch_bounds__(256) void cluster_kernel(
    const float* __restrict__ k, const float* __restrict__ v,
    const float* __restrict__ smooth, const int* __restrict__ meta,
    unsigned short* __restrict__ kcfh, unsigned short* __restrict__ kcfl,
    unsigned short* __restrict__ vcfh, unsigned short* __restrict__ vcfl)
{
  int c = blockIdx.x, b = blockIdx.y;
  int C = meta[0], lo = meta[1], n_cl = meta[3];
  if (c >= n_cl) return;
  const float* sm = smooth + b * SPAT + lo + c * C;

  float m = sm[0];
  for (int j = 1; j < C; ++j) m = fmaxf(m, sm[j]);
  float S = 0.f;
  for (int j = 0; j < C; ++j) S += __expf(sm[j] - m);
  float invS = 1.f / S;

  int d = threadIdx.x;
  int s0 = lo + c * C;
  const float* kp = k + (s0 * BSZ + b) * DM + d;
  const float* vp = v + (s0 * BSZ + b) * DM + d;
  float ak = 0.f, av = 0.f;
  for (int j = 0; j < C; ++j) {
    float wj = __expf(sm[j] - m) * invS;
    ak += wj * kp[0];
    av += wj * vp[0];
    kp += BSZ * DM; vp += BSZ * DM;
  }
  int rowg = b * SPAT + c;
  size_t dst = (((size_t)(rowg >> 4) * 8 + (d >> 5)) * 64
                + ((d >> 3) & 3) * 16 + (rowg & 15)) * 8 + (d & 7);
  unsigned short hb = f2bf(ak);
  kcfh[dst] = hb; kcfl[dst] = (unsigned short)f2bf(ak - bf2f(hb));
  hb = f2bf(av);
  vcfh[dst] = hb; vcfl[dst] = (unsigned short)f2bf(av - bf2f(hb));
}

// -------- shared GEMM body: fragment-linear operands, bf16x3, unroll 2 ----
static __device__ __forceinline__ void gemm_body(
    const unsigned short* __restrict__ Afh, const unsigned short* __restrict__ Afl,
    const unsigned short* __restrict__ Bfh, const unsigned short* __restrict__ Bfl,
    const float* __restrict__ bias,
    unsigned short* __restrict__ Oh, unsigned short* __restrict__ Ol,
    float* __restrict__ Of, int epi, int skipcl, const int* __restrict__ meta)
{
  int row0blk = blockIdx.x * 64;
  if (skipcl && (row0blk % SPAT) >= meta[3]) return;
  int wv = threadIdx.x >> 6, l = threadIdx.x & 63;
  int g = l >> 4, sig = l & 15;
  int row0 = row0blk + wv * 16;
  int rtile = row0 >> 4;
  int col0 = blockIdx.y * 64;
  int ntile0 = col0 >> 4;

  f32x4 acc[4] = {{0.f,0.f,0.f,0.f},{0.f,0.f,0.f,0.f},{0.f,0.f,0.f,0.f},{0.f,0.f,0.f,0.f}};

  #pragma unroll 2
  for (int kt = 0; kt < 8; ++kt) {
    size_t ao = (((size_t)rtile * 8 + kt) * 64 + l) * 8;
    bf16x8 ah = *(const bf16x8*)(Afh + ao);
    bf16x8 al = *(const bf16x8*)(Afl + ao);
    #pragma unroll
    for (int nt = 0; nt < 4; ++nt) {
      size_t bo = (((size_t)(ntile0 + nt) * 8 + kt) * 64 + l) * 8;
      bf16x8 bh = *(const bf16x8*)(Bfh + bo);
      bf16x8 bl = *(const bf16x8*)(Bfl + bo);
      acc[nt] = __builtin_amdgcn_mfma_f32_16x16x32_bf16(ah, bh, acc[nt], 0, 0, 0);
      acc[nt] = __builtin_amdgcn_mfma_f32_16x16x32_bf16(al, bh, acc[nt], 0, 0, 0);
      acc[nt] = __builtin_amdgcn_mfma_f32_16x16x32_bf16(ah, bl, acc[nt], 0, 0, 0);
    }
  }

  int bb = row0 / SPAT;
  int sbase = row0 - bb * SPAT + 4 * g;
  #pragma unroll
  for (int nt = 0; nt < 4; ++nt) {
    int n = col0 + nt * 16 + sig;
    float bi = bias[n];
    if (epi == 0) {
      int h = n >> 5, dl = n & 31;
      size_t base = (size_t)(bb * NH + h) * SPAT * DH + dl;
      #pragma unroll
      for (int r = 0; r < 4; ++r) {
        float x = acc[nt][r] + bi;
        unsigned short hb = f2bf(x);
        size_t dst = base + (size_t)(sbase + r) * DH;
        Oh[dst] = hb;
        Ol[dst] = (unsigned short)f2bf(x - bf2f(hb));
      }
    } else if (epi == 1) {
      int h = n >> 5;
      int bh = bb * NH + h;
      int dhalf = (n & 31) >> 4;
      int mrow = n & 15;
      #pragma unroll
      for (int r = 0; r < 4; ++r) {
        int c = sbase + r;
        float x = acc[nt][r] + bi;
        unsigned short hb = f2bf(x);
        size_t dst = ((((size_t)bh * NC16 + (c >> 4)) * 2 + dhalf) * 64
                      + ((c >> 2) & 3) * 16 + mrow) * 4 + (c & 3);
        Oh[dst] = hb;
        Ol[dst] = (unsigned short)f2bf(x - bf2f(hb));
      }
    } else {
      #pragma unroll
      for (int r = 0; r < 4; ++r) {
        float x = acc[nt][r] + bi;
        Of[(size_t)((sbase + r) * BSZ + bb) * DM + n] = x;
      }
    }
  }
}

// -------- K5a: fused Q/K/V projection GEMMs (blockIdx.z selects) --------
__global__ __launch_bounds__(256) void mfma_gemm_qkv_kernel(
    const unsigned short* __restrict__ qfh, const unsigned short* __restrict__ qfl,
    const unsigned short* __restrict__ kcfh, const unsigned short* __restrict__ kcfl,
    const unsigned short* __restrict__ vcfh, const unsigned short* __restrict__ vcfl,
    const unsigned short* __restrict__ WTfh, const unsigned short* __restrict__ WTfl,
    const float* __restrict__ bq, const float* __restrict__ bk, const float* __restrict__ bv,
    unsigned short* __restrict__ Qh, unsigned short* __restrict__ Ql,
    unsigned short* __restrict__ Kh, unsigned short* __restrict__ Kl,
    unsigned short* __restrict__ Vth, unsigned short* __restrict__ Vtl,
    const int* __restrict__ meta)
{
  int z = blockIdx.z;
  if (z == 0) {
    gemm_body(qfh, qfl, WTfh, WTfl, bq, Qh, Ql, nullptr, 0, 0, meta);
  } else if (z == 1) {
    gemm_body(kcfh, kcfl, WTfh + DM * DM, WTfl + DM * DM, bk, Kh, Kl, nullptr, 0, 1, meta);
  } else {
    gemm_body(vcfh, vcfl, WTfh + 2 * DM * DM, WTfl + 2 * DM * DM, bv, Vth, Vtl, nullptr, 1, 1, meta);
  }
}

// -------- K5b: output GEMM (epi=2, fp32 out + transpose) --------
__global__ __launch_bounds__(256) void mfma_gemm_o_kernel(
    const unsigned short* __restrict__ Afh, const unsigned short* __restrict__ Afl,
    const unsigned short* __restrict__ Bfh, const unsigned short* __restrict__ Bfl,
    const float* __restrict__ bias, float* __restrict__ Of,
    const int* __restrict__ meta)
{
  gemm_body(Afh, Afl, Bfh, Bfl, bias, nullptr, nullptr, Of, 2, 0, meta);
}

// -------- K6: MFMA attention (XCD-pinned grid + intra-block wave stagger).
// FINAL config — measured best, reproduced twice (115.9 / 116.2 us total;
// attn 42.0 us, VGPR 56, occ 28%, FETCH 9 MB). Probed and rejected:
// MLP-widen (r15, -59%), cross-block rotation (r16, -4%), K ping-pong
// (r19, -8%), 2x cluster-split (r21, -5%). attn is at its latency floor
// for this decomposition. QK bf16x3; PV K=16 fed from QK output regs.
__global__ __launch_bounds__(256) void attn_mfma_kernel(
    const unsigned short* __restrict__ Qh, const unsigned short* __restrict__ Ql,
    const unsigned short* __restrict__ Kh, const unsigned short* __restrict__ Kl,
    const unsigned short* __restrict__ Vth, const unsigned short* __restrict__ Vtl,
    const int* __restrict__ meta,
    unsigned short* __restrict__ ctxfh, unsigned short* __restrict__ ctxfl)
{
  int bh = blockIdx.x;                      // 0..63 -> XCD = bh % 8
  int b = bh >> 3, h = bh & 7;
  int t = threadIdx.x;
  int w = t >> 6, l = t & 63;
  int g = l >> 4, sig = l & 15;
  int n_cl = meta[3];
  int s = blockIdx.y * 64 + w * 16 + sig;   // 25*64 = 1600

  size_t qoff = ((size_t)bh * SPAT + s) * DH + g * 8;
  bf16x8 qh = *(const bf16x8*)(Qh + qoff);
  bf16x8 ql = *(const bf16x8*)(Ql + qoff);

  const unsigned short* Kbh = Kh + (size_t)bh * SPAT * DH;
  const unsigned short* Kbl = Kl + (size_t)bh * SPAT * DH;
  const unsigned short* Vbh = Vth + (size_t)bh * NC16 * 2 * 64 * 4;
  const unsigned short* Vbl = Vtl + (size_t)bh * NC16 * 2 * 64 * 4;

  f32x4 o0 = {0.f, 0.f, 0.f, 0.f}, o1 = {0.f, 0.f, 0.f, 0.f};
  float m = -1e30f, lsum = 0.f;

  int nch = (n_cl + 63) >> 6;
  int start = (w * nch) >> 2;               // {0, n/4, n/2, 3n/4}

  for (int i = 0; i < nch; ++i) {
    int ci = start + i;
    if (ci >= nch) ci -= nch;
    int c0 = ci * 64;

    // ---- QK^T: rows cr = c0+ct*16+sig <= 1599 always (c0 <= 1536) ----
    f32x4 sc[4];
    __builtin_amdgcn_s_setprio(1);
    #pragma unroll
    for (int ct = 0; ct < 4; ++ct) {
      size_t ko = (size_t)(c0 + ct * 16 + sig) * DH + g * 8;
      bf16x8 kh = *(const bf16x8*)(Kbh + ko);
      bf16x8 kl = *(const bf16x8*)(Kbl + ko);
      f32x4 a = {0.f, 0.f, 0.f, 0.f};
      a = __builtin_amdgcn_mfma_f32_16x16x32_bf16(kh, qh, a, 0, 0, 0);
      a = __builtin_amdgcn_mfma_f32_16x16x32_bf16(kh, ql, a, 0, 0, 0);
      a = __builtin_amdgcn_mfma_f32_16x16x32_bf16(kl, qh, a, 0, 0, 0);
      sc[ct] = a;
    }
    __builtin_amdgcn_s_setprio(0);

    // ---- V A-frags for this chunk: issue BEFORE softmax (independent) ----
    bf16x4 vfh[4][2], vfl[4][2];
    #pragma unroll
    for (int ct = 0; ct < 4; ++ct) {
      int c16 = (c0 >> 4) + ct;             // <= 99, always in-buffer
      #pragma unroll
      for (int dh2 = 0; dh2 < 2; ++dh2) {
        size_t vo = (((size_t)c16 * 2 + dh2) * 64 + l) * 4;
        vfh[ct][dh2] = *(const bf16x4*)(Vbh + vo);
        vfl[ct][dh2] = *(const bf16x4*)(Vbl + vo);
      }
    }

    if (c0 + 64 > n_cl) {                   // tail chunk only: mask
      #pragma unroll
      for (int ct = 0; ct < 4; ++ct) {
        #pragma unroll
        for (int r = 0; r < 4; ++r) {
          int c = c0 + ct * 16 + g * 4 + r;
          if (c >= n_cl) sc[ct][r] = -INFINITY;
        }
      }
    }
    float mc = sc[0][0];
    #pragma unroll
    for (int ct = 0; ct < 4; ++ct) {
      #pragma unroll
      for (int r = 0; r < 4; ++r) mc = fmaxf(mc, sc[ct][r]);
    }
    mc = fmaxf(mc, __shfl_xor(mc, 16));
    mc = fmaxf(mc, __shfl_xor(mc, 32));
    float nm = fmaxf(m, mc);
    float corr = __expf(m - nm);
    m = nm;
    lsum *= corr; o0 *= corr; o1 *= corr;
    float ls0 = 0.f, ls1 = 0.f;
    #pragma unroll
    for (int ct = 0; ct < 4; ++ct) {
      #pragma unroll
      for (int r = 0; r < 4; ++r) {
        float p = __expf(sc[ct][r] - m);
        sc[ct][r] = p;
        if (ct < 2) ls0 += p; else ls1 += p;
      }
    }
    lsum += ls0 + ls1;

    // ---- PV: P already in B-frag layout for 16x16x16 (k = 4g+j) ----
    __builtin_amdgcn_s_setprio(1);
    #pragma unroll
    for (int ct = 0; ct < 4; ++ct) {
      if (c0 + ct * 16 >= n_cl) continue;   // wave-uniform skip
      bf16x4 pb;
      #pragma unroll
      for (int j = 0; j < 4; ++j) pb[j] = (short)f2bf(sc[ct][j]);
      o0 = __builtin_amdgcn_mfma_f32_16x16x16bf16_1k(vfh[ct][0], pb, o0, 0, 0, 0);
      o0 = __builtin_amdgcn_mfma_f32_16x16x16bf16_1k(vfl[ct][0], pb, o0, 0, 0, 0);
      o1 = __builtin_amdgcn_mfma_f32_16x16x16bf16_1k(vfh[ct][1], pb, o1, 0, 0, 0);
      o1 = __builtin_amdgcn_mfma_f32_16x16x16bf16_1k(vfl[ct][1], pb, o1, 0, 0, 0);
    }
    __builtin_amdgcn_s_setprio(0);
  }

  // ---- finalize: write O^T frags into ctx A-fragment layout ----
  lsum += __shfl_xor(lsum, 16);
  lsum += __shfl_xor(lsum, 32);
  float inv = 1.f / (lsum * 32.f);
  int rowg = b * SPAT + s;                  // rowg&15 == sig
  size_t tb = (((size_t)(rowg >> 4) * 8 + h) * 64 + sig) * 8 + (g & 1) * 4;
  size_t off0 = tb + (size_t)(g >> 1) * 128;        // d = 4g+r  (ktile=h)
  size_t off1 = tb + (size_t)(2 + (g >> 1)) * 128;  // d = 16+4g+r
  u16x4 hv0, lv0, hv1, lv1;
  #pragma unroll
  for (int r = 0; r < 4; ++r) {
    float x0 = o0[r] * inv;
    unsigned short h0 = f2bf(x0);
    hv0[r] = h0; lv0[r] = (unsigned short)f2bf(x0 - bf2f(h0));
    float x1 = o1[r] * inv;
    unsigned short h1 = f2bf(x1);
    hv1[r] = h1; lv1[r] = (unsigned short)f2bf(x1 - bf2f(h1));
  }
  *(u16x4*)(ctxfh + off0) = hv0;
  *(u16x4*)(ctxfl + off0) = lv0;
  *(u16x4*)(ctxfh + off1) = hv1;
  *(u16x4*)(ctxfl + off1) = lv1;
}

extern "C" void kernel_launch(void* const* d_in, const int* in_sizes, int n_in,
                              void* d_out, int out_size, void* d_ws, size_t ws_size,
                              hipStream_t stream) {
  const float* q  = (const float*)d_in[0];
  const float* k  = (const float*)d_in[1];
  const float* v  = (const float*)d_in[2];
  const float* Wq = (const float*)d_in[5];
  const float* bq = (const float*)d_in[6];
  const float* Wk = (const float*)d_in[7];
  const float* bk = (const float*)d_in[8];
  const float* Wv = (const float*)d_in[9];
  const float* bv = (const float*)d_in[10];
  const float* Wo = (const float*)d_in[11];
  const float* bo = (const float*)d_in[12];
  const float* Wp = (const float*)d_in[13];
  const float* bp = (const float*)d_in[14];
  const float* gk = (const float*)d_in[15];
  const float* sb = (const float*)d_in[16];
  float* out = (float*)d_out;

  const size_t NE = (size_t)BSZ * SPAT * DM;                 // 3276800
  char* ws = (char*)d_ws;
  int*   meta   = (int*)ws;                                  // 256 B
  float* logits = (float*)(ws + 256);                        // 12800 f32
  float* smooth = logits + BSZ * SPAT;                       // 12800 f32
  unsigned short* kcfh = (unsigned short*)(ws + 256 + 2 * BSZ * SPAT * 4);
  unsigned short* kcfl = kcfh + NE;
  unsigned short* vcfh = kcfl + NE;
  unsigned short* vcfl = vcfh + NE;
  unsigned short* qfh  = vcfl + NE;
  unsigned short* qfl  = qfh + NE;
  unsigned short* Qh   = qfl + NE;
  unsigned short* Ql   = Qh + NE;
  unsigned short* Kh   = Ql + NE;
  unsigned short* Kl   = Kh + NE;
  unsigned short* Vth  = Kl + NE;   // NOT aliased: QKV GEMMs fused in one
  unsigned short* Vtl  = Vth + NE;  // dispatch — z=0 reads qf while z=2 writes
  unsigned short* WTfh = Vtl + NE;                           // 4*65536 u16
  unsigned short* WTfl = WTfh + 4 * DM * DM;
  unsigned short* ctxfh = kcfh;     // alias kcf (dead after fused QKV GEMM)
  unsigned short* ctxfl = kcfl;

  prep_logits_kernel<<<4832, 256, 0, stream>>>(
      k, Wp, bp, logits, q, Wq, Wk, Wv, Wo, qfh, qfl, WTfh, WTfl);
  entropy_kernel<<<BSZ, 512, 0, stream>>>(logits, gk, smooth);
  clsize_kernel<<<1, 512, 0, stream>>>(smooth, sb, meta);
  cluster_kernel<<<dim3(SPAT, BSZ), 256, 0, stream>>>(
      k, v, smooth, meta, kcfh, kcfl, vcfh, vcfl);
  mfma_gemm_qkv_kernel<<<dim3(200, 4, 3), 256, 0, stream>>>(
      qfh, qfl, kcfh, kcfl, vcfh, vcfl, WTfh, WTfl, bq, bk, bv,
      Qh, Ql, Kh, Kl, Vth, Vtl, meta);
  attn_mfma_kernel<<<dim3(64, 25), 256, 0, stream>>>(
      Qh, Ql, Kh, Kl, Vth, Vtl, meta, ctxfh, ctxfl);
  mfma_gemm_o_kernel<<<dim3(200, 4), 256, 0, stream>>>(
      ctxfh, ctxfl, WTfh + 3 * DM * DM, WTfl + 3 * DM * DM, bo, out, meta);
}